// Round 8
// baseline (462.270 us; speedup 1.0000x reference)
//
#include <hip/hip_runtime.h>
#include <float.h>

#define BATCH 16
#define NPTS  65536
#define NP    64      // NUM_PATCHES
#define PS    32      // PATCH_SIZE
#define SLICES 2
#define SLICE_PTS (NPTS / SLICES)   // 32768
#define CAP   256                   // per (center,slice) candidate cap (exp ~50)

// Selection math (FPS argmax, KNN top-32) is float64 on f32 inputs (products
// of f32 exact in f64 -> bit-identical to numpy f64 regardless of FMA), with
// numpy expression order: ((a+b)+c), d2 = (c2+p2) - 2*dot, contract(off).
// Keys: trunc-48-bit f64 ordering bits | 16-bit index -> (dist, idx) lex order.
//
// FUSION: fps (blocks 0..255) and knn (blocks 256..767) run in ONE kernel.
// knn WGs derive their centers by polling the fps slots array directly (the
// u64 winner key encodes the point index; P is immutable -> relaxed atomics
// suffice, same argument as fps's own sync). Grid 768 <= guaranteed capacity
// (launch_bounds(256,4): <=128 VGPR -> 4 WGs/CU -> 1024; LDS 12.4KB -> 12/CU)
// so ALL WGs are co-resident regardless of dispatch order -> deadlock-free.

__device__ __forceinline__ unsigned long long enc64(double d) {
    unsigned long long u = (unsigned long long)__double_as_longlong(d);
    return u ^ ((u >> 63) ? 0xFFFFFFFFFFFFFFFFull : 0x8000000000000000ull);
}
__device__ __forceinline__ unsigned enc32(float f) {
    unsigned u = __float_as_uint(f);
    return u ^ ((u >> 31) ? 0xFFFFFFFFu : 0x80000000u);
}
__device__ __forceinline__ float dec32(unsigned e) {
    unsigned u = (e & 0x80000000u) ? (e ^ 0x80000000u) : ~e;
    return __uint_as_float(u);
}

#define SENT 0xFFFFFFFFFFFFFFFFull

__global__ __launch_bounds__(256, 4)
void fused_kernel(const float* __restrict__ pts,
                  float* __restrict__ centers,               // [16][64][3]
                  unsigned long long* __restrict__ slots,    // [16][63][16], zeroed
                  unsigned long long* __restrict__ gkeys)    // [1024][2][32]
{
    const int t    = threadIdx.x;
    const int lane = t & 63;
    const int wid  = t >> 6;

    // shared: fps uses wbest/skey; knn uses pool/idxbuf/theta/cnt4
    __shared__ unsigned long long wbest[4];
    __shared__ unsigned long long skey[16];
    __shared__ unsigned pool[4][512];
    __shared__ float    theta[4];
    __shared__ int      cnt4[4];
    __shared__ unsigned idxbuf[4][CAP];

    if (blockIdx.x < 256) {
        // ================= FPS path (measured structure from R5/R6) =========
#pragma clang fp contract(off)
        __builtin_amdgcn_s_setprio(3);   // win VALU arbitration vs knn waves
        const int b  = blockIdx.x & 15;
        const int wg = blockIdx.x >> 4;
        const float* __restrict__ P = pts + (size_t)b * NPTS * 3;

        float x[16], y[16], z[16];
        double md[16];
        const int gi0 = wg * 4096 + t;
#pragma unroll
        for (int k = 0; k < 16; ++k) {
            int i = gi0 + (k << 8);
            x[k] = P[3*i+0]; y[k] = P[3*i+1]; z[k] = P[3*i+2];
            md[k] = DBL_MAX;
        }

        double cx = (double)P[0], cy = (double)P[1], cz = (double)P[2];
        if (wg == 0 && t == 0) {
            float* c0 = centers + b * (NP*3);
            c0[0] = P[0]; c0[1] = P[1]; c0[2] = P[2];
        }

        unsigned long long* slot_it = slots + (size_t)b * 63 * 16;

        for (int it = 0; it < NP - 1; ++it) {
            double bd = -1.0; int bi = 0;
#pragma unroll
            for (int k = 0; k < 16; ++k) {
                double dx = (double)x[k] - cx;
                double dy = (double)y[k] - cy;
                double dz = (double)z[k] - cz;
                double d  = (dx*dx + dy*dy) + dz*dz;   // numpy add order
                double m  = fmin(md[k], d);
                md[k] = m;
                if (m > bd) { bd = m; bi = gi0 + (k << 8); }
            }
            unsigned long long db  = (unsigned long long)__double_as_longlong(bd);
            unsigned long long key = 0x8000000000000000ull
                                   | (db & 0xFFFFFFFFFFFF0000ull)
                                   | (unsigned long long)((~bi) & 0xFFFF);
#pragma unroll
            for (int off = 32; off > 0; off >>= 1) {
                unsigned long long o = __shfl_xor(key, off, 64);
                if (o > key) key = o;
            }
            if ((t & 63) == 0) wbest[t >> 6] = key;
            __syncthreads();
            if (t == 0) {
                unsigned long long k0 = wbest[0];
                if (wbest[1] > k0) k0 = wbest[1];
                if (wbest[2] > k0) k0 = wbest[2];
                if (wbest[3] > k0) k0 = wbest[3];
                __hip_atomic_store(slot_it + wg, k0, __ATOMIC_RELAXED, __HIP_MEMORY_SCOPE_AGENT);
            }
            if (t < 16) {
                unsigned long long v;
                v = __hip_atomic_load(slot_it + t, __ATOMIC_RELAXED, __HIP_MEMORY_SCOPE_AGENT);
                while (v == 0) {
                    __builtin_amdgcn_s_sleep(1);
                    v = __hip_atomic_load(slot_it + t, __ATOMIC_RELAXED, __HIP_MEMORY_SCOPE_AGENT);
                }
                skey[t] = v;
            }
            __syncthreads();
            unsigned long long bk = skey[0];
#pragma unroll
            for (int j = 1; j < 16; ++j) if (skey[j] > bk) bk = skey[j];
            int sel = (int)((~bk) & 0xFFFFull);
            cx = (double)P[3*sel+0]; cy = (double)P[3*sel+1]; cz = (double)P[3*sel+2];
            if (wg == 0 && t == 0) {
                float* c = centers + b*(NP*3) + (it+1)*3;
                c[0] = P[3*sel+0]; c[1] = P[3*sel+1]; c[2] = P[3*sel+2];
            }
            __syncthreads();
            slot_it += 16;
        }
        return;
    }

    // ===================== KNN path =========================================
    __builtin_amdgcn_s_setprio(0);
    const int id = blockIdx.x - 256;     // 0..511
    const int b  = id & 15;              // XCD-local with fps of same batch
    const int w  = (id >> 4) & 15;       // center group of 4
    const int s  = id >> 8;              // slice 0..1
    const float* __restrict__ P = pts + (size_t)b * NPTS * 3;
    const int sbase = s * SLICE_PTS;

    // ---- wait for centers 4w..4w+3 by polling fps slots directly ----
    // lane l: round = 4w-1 + (l>>4), slot = l&15. round==-1 => center 0 = P[0].
    {
        int rnd = 4*w - 1 + (lane >> 4);
        unsigned long long key;
        if (rnd >= 0) {
            const unsigned long long* sp = slots + ((size_t)b*63 + rnd)*16 + (lane & 15);
            unsigned long long v = __hip_atomic_load(sp, __ATOMIC_RELAXED, __HIP_MEMORY_SCOPE_AGENT);
            while (v == 0) {
                __builtin_amdgcn_s_sleep(8);
                v = __hip_atomic_load(sp, __ATOMIC_RELAXED, __HIP_MEMORY_SCOPE_AGENT);
            }
            key = v;
        } else {
            key = 0xFFFFull;             // ~key & 0xFFFF == 0  -> sel = 0
        }
#pragma unroll
        for (int off = 1; off <= 8; off <<= 1) {   // max within 16-lane group
            unsigned long long o = __shfl_xor(key, off, 64);
            if (o > key) key = o;
        }
        int selv = (int)((~key) & 0xFFFFull);
        // broadcast the 4 group winners to all lanes
        int sg0 = __shfl(selv,  0, 64);
        int sg1 = __shfl(selv, 16, 64);
        int sg2 = __shfl(selv, 32, 64);
        int sg3 = __shfl(selv, 48, 64);
        if (t == 0) { idxbuf[0][0]=(unsigned)sg0; idxbuf[1][0]=(unsigned)sg1;
                      idxbuf[2][0]=(unsigned)sg2; idxbuf[3][0]=(unsigned)sg3; }
        __syncthreads();
    }

    float cxf[4], cyf[4], czf[4], c2f[4];
#pragma unroll
    for (int g = 0; g < 4; ++g) {
        int sel = (int)idxbuf[g][0];
        cxf[g] = P[3*sel+0]; cyf[g] = P[3*sel+1]; czf[g] = P[3*sel+2];
        c2f[g] = cxf[g]*cxf[g] + cyf[g]*cyf[g] + czf[g]*czf[g];
    }
    __syncthreads();

    // ---- pass 1: per-thread top-2 (f32), 128 pts/thread, coalesced ----
    float s0[4], s1[4];
#pragma unroll
    for (int g = 0; g < 4; ++g) { s0[g] = FLT_MAX; s1[g] = FLT_MAX; }
    for (int k = 0; k < SLICE_PTS/256; ++k) {        // 128
        int i = sbase + (k << 8) + t;
        const float* p = P + 3*i;
        float px = p[0], py = p[1], pz = p[2];
        float p2 = px*px + py*py + pz*pz;
#pragma unroll
        for (int g = 0; g < 4; ++g) {
            float dt = cxf[g]*px + cyf[g]*py + czf[g]*pz;
            float d2 = (c2f[g] + p2) - 2.0f*dt;
            float mx = fmaxf(d2, s0[g]);
            s0[g] = fminf(s0[g], d2);
            s1[g] = fminf(s1[g], mx);
        }
    }
#pragma unroll
    for (int g = 0; g < 4; ++g) {
        pool[g][t]       = enc32(s0[g]);
        pool[g][256 + t] = enc32(s1[g]);
    }
    if (t < 4) cnt4[t] = 0;
    __syncthreads();

    // ---- theta: wave wid finds 32nd smallest of pool[wid][0..511] ----
    {
        const int g = wid;
        unsigned e[8];
#pragma unroll
        for (int j = 0; j < 8; ++j) e[j] = pool[g][lane * 8 + j];
        unsigned ans = 0;
        for (int bit = 31; bit >= 0; --bit) {
            unsigned test = ans | ((1u << bit) - 1u);
            int cnt = 0;
#pragma unroll
            for (int j = 0; j < 8; ++j)
                cnt += (int)__popcll(__ballot(e[j] <= test));
            if (cnt < 32) ans |= (1u << bit);
        }
        if (lane == 0) theta[g] = dec32(ans) + 4.0e-3f;
    }
    __syncthreads();
    float th[4];
#pragma unroll
    for (int g = 0; g < 4; ++g) th[g] = theta[g];

    // ---- pass 2: f32 rescan, record indices only ----
    for (int k = 0; k < SLICE_PTS/256; ++k) {
        int i = sbase + (k << 8) + t;
        const float* p = P + 3*i;
        float px = p[0], py = p[1], pz = p[2];
        float p2 = px*px + py*py + pz*pz;
#pragma unroll
        for (int g = 0; g < 4; ++g) {
            float dt = cxf[g]*px + cyf[g]*py + czf[g]*pz;
            float d2 = (c2f[g] + p2) - 2.0f*dt;
            bool hit = (d2 <= th[g]);
            unsigned long long m = __ballot(hit);
            if (m) {
                int ldr = __ffsll(m) - 1;
                int base = 0;
                if (lane == ldr) base = atomicAdd(&cnt4[g], (int)__popcll(m));
                base = __shfl(base, ldr, 64);
                if (hit) {
                    int pos = base + (int)__popcll(m & ((1ull << lane) - 1ull));
                    if (pos < CAP) idxbuf[g][pos] = (unsigned)i;
                }
            }
        }
    }
    __syncthreads();

    // ---- phase 3: wave wid -> center wid: exact f64 keys, top-32 sorted ----
    {
        const int g = wid;
        int n = cnt4[g]; if (n > CAP) n = CAP;
        double cxd, cyd, czd, c2d;
        {
#pragma clang fp contract(off)
            cxd = (double)cxf[g]; cyd = (double)cyf[g]; czd = (double)czf[g];
            c2d = (cxd*cxd + cyd*cyd) + czd*czd;
        }
        unsigned long long rg[4];
#pragma unroll
        for (int j = 0; j < 4; ++j) {
            int p_ = lane + 64*j;
            if (p_ < n) {
                unsigned i = idxbuf[g][p_];
                double d2x;
                {
#pragma clang fp contract(off)
                    double px_ = (double)P[3*i+0];
                    double py_ = (double)P[3*i+1];
                    double pz_ = (double)P[3*i+2];
                    double p2_ = (px_*px_ + py_*py_) + pz_*pz_;
                    double dt_ = (cxd*px_ + cyd*py_) + czd*pz_;
                    d2x = (c2d + p2_) - 2.0*dt_;
                }
                rg[j] = (enc64(d2x) & 0xFFFFFFFFFFFF0000ull)
                      | (unsigned long long)(i & 0xFFFF);
            } else rg[j] = SENT;
        }
        const int c = b * NP + w * 4 + g;
        unsigned long long okey = SENT;
        for (int r = 0; r < PS; ++r) {
            unsigned long long mn = rg[0]; int mp = 0;
            if (rg[1] < mn) { mn = rg[1]; mp = 1; }
            if (rg[2] < mn) { mn = rg[2]; mp = 2; }
            if (rg[3] < mn) { mn = rg[3]; mp = 3; }
            unsigned long long wm = mn;
#pragma unroll
            for (int off = 32; off > 0; off >>= 1) {
                unsigned long long o = __shfl_xor(wm, off, 64);
                if (o < wm) wm = o;
            }
            if (wm == mn) {
                if (mp == 0) rg[0] = SENT;
                else if (mp == 1) rg[1] = SENT;
                else if (mp == 2) rg[2] = SENT;
                else rg[3] = SENT;
            }
            if (lane == r) okey = wm;
        }
        if (lane < PS)
            gkeys[((size_t)c * SLICES + s) * PS + lane] = okey;
    }
}

// ---------------------------------------------------------------------------
// Merge: 256 WGs x 256 thr; wave wid handles center b*64+grp*4+wid. Reads the
// 2 sorted 32-key lists (64 keys, 1/lane), 32 extraction rounds -> global
// top-32 in lax.top_k order; lanes 0..31 gather P and write patch rows.
// ---------------------------------------------------------------------------
__global__ __launch_bounds__(256, 4)
void knn_merge(const float* __restrict__ pts,
               const float* __restrict__ centers,
               const unsigned long long* __restrict__ gkeys,
               float* __restrict__ patches)
{
    const int lane = threadIdx.x & 63;
    const int wid  = threadIdx.x >> 6;
    const int b    = blockIdx.x & 15;
    const int grp  = blockIdx.x >> 4;
    const int c    = b * NP + grp * 4 + wid;
    const float* __restrict__ P = pts + (size_t)b * NPTS * 3;

    unsigned long long kv = gkeys[(size_t)c * (SLICES*PS) + lane];

    unsigned long long okey = SENT;
    for (int r = 0; r < PS; ++r) {
        unsigned long long wm = kv;
#pragma unroll
        for (int off = 32; off > 0; off >>= 1) {
            unsigned long long o = __shfl_xor(wm, off, 64);
            if (o < wm) wm = o;
        }
        if (kv == wm) kv = SENT;        // unique (idx embedded in key)
        if (lane == r) okey = wm;
    }

    const float cx = centers[3*c+0], cy = centers[3*c+1], cz = centers[3*c+2];
    if (lane < PS) {
        int i = (int)(okey & 0xFFFFull);
        float* o = patches + (((size_t)c * PS) + lane) * 3;
        o[0] = P[3*i+0] - cx;
        o[1] = P[3*i+1] - cy;
        o[2] = P[3*i+2] - cz;
    }
}

extern "C" void kernel_launch(void* const* d_in, const int* in_sizes, int n_in,
                              void* d_out, int out_size, void* d_ws, size_t ws_size,
                              hipStream_t stream)
{
    const float* pts = (const float*)d_in[0];
    float* out      = (float*)d_out;
    float* patches  = out;                          // [16][64][32][3] = 98304
    float* centers  = out + (size_t)BATCH*NP*PS*3;  // [16][64][3]     = 3072

    unsigned long long* slots = (unsigned long long*)d_ws;                   // 129 KB
    unsigned long long* gkeys = (unsigned long long*)((char*)d_ws + 131072); // 512 KB

    (void)hipMemsetAsync(d_ws, 0, (size_t)BATCH * 63 * 16 * sizeof(unsigned long long), stream);
    fused_kernel<<<dim3(768), dim3(256), 0, stream>>>(pts, centers, slots, gkeys);
    knn_merge<<<dim3(256), dim3(256), 0, stream>>>(pts, centers, gkeys, patches);
}

// Round 9
// 265.397 us; speedup vs baseline: 1.7418x; 1.7418x over previous
//
#include <hip/hip_runtime.h>
#include <float.h>

#define BATCH 16
#define NPTS  65536
#define NP    64      // NUM_PATCHES
#define PS    32      // PATCH_SIZE
#define SLICES 8
#define SLICE_PTS (NPTS / SLICES)   // 8192
#define CAP   192                   // per (center,slice) candidate cap (exp ~40)

// Selection math (FPS argmax, KNN top-32) is float64 on f32 inputs (products
// of f32 exact in f64 -> bit-identical to numpy f64 regardless of FMA), with
// numpy expression order: ((a+b)+c), d2 = (c2+p2) - 2*dot, contract(off).
// Keys: trunc-48-bit f64 ordering bits | 16-bit index -> (dist, idx) lex order.

__device__ __forceinline__ unsigned long long enc64(double d) {
    unsigned long long u = (unsigned long long)__double_as_longlong(d);
    return u ^ ((u >> 63) ? 0xFFFFFFFFFFFFFFFFull : 0x8000000000000000ull);
}
__device__ __forceinline__ unsigned enc32(float f) {
    unsigned u = __float_as_uint(f);
    return u ^ ((u >> 31) ? 0xFFFFFFFFu : 0x80000000u);
}
__device__ __forceinline__ float dec32(unsigned e) {
    unsigned u = (e & 0x80000000u) ? (e ^ 0x80000000u) : ~e;
    return __uint_as_float(u);
}

#define SENT 0xFFFFFFFFFFFFFFFFull

// ---------------------------------------------------------------------------
// FPS: 16 WGs per batch (blockIdx = wg*16+b -> all WGs of batch b on XCD b%8),
// 256 threads, 16 pts/thread in VGPRs. Relaxed agent atomics only. 2 barriers
// per round (trailing barrier removed: bar1 of round it+1 already orders all
// skey/wbest reuse — any wave's next write requires every wave to have passed
// this round's reads).
// ---------------------------------------------------------------------------
__global__ __launch_bounds__(256, 2)
void fps_kernel(const float* __restrict__ pts,
                float* __restrict__ centers,               // [16][64][3]
                unsigned long long* __restrict__ slots)    // [16][63][16], zeroed
{
#pragma clang fp contract(off)
    const int b  = blockIdx.x & 15;
    const int wg = blockIdx.x >> 4;
    const int t  = threadIdx.x;
    const float* __restrict__ P = pts + (size_t)b * NPTS * 3;

    float x[16], y[16], z[16];
    double md[16];
    const int gi0 = wg * 4096 + t;
#pragma unroll
    for (int k = 0; k < 16; ++k) {
        int i = gi0 + (k << 8);
        x[k] = P[3*i+0]; y[k] = P[3*i+1]; z[k] = P[3*i+2];
        md[k] = DBL_MAX;
    }

    double cx = (double)P[0], cy = (double)P[1], cz = (double)P[2]; // start idx 0
    if (wg == 0 && t == 0) {
        float* c0 = centers + b * (NP*3);
        c0[0] = P[0]; c0[1] = P[1]; c0[2] = P[2];
    }

    __shared__ unsigned long long wbest[4];
    __shared__ unsigned long long skey[16];

    unsigned long long* slot_it = slots + (size_t)b * 63 * 16;

    for (int it = 0; it < NP - 1; ++it) {
        double bd = -1.0; int bi = 0;
#pragma unroll
        for (int k = 0; k < 16; ++k) {
            double dx = (double)x[k] - cx;
            double dy = (double)y[k] - cy;
            double dz = (double)z[k] - cz;
            double d  = (dx*dx + dy*dy) + dz*dz;   // numpy add order (products exact)
            double m  = fmin(md[k], d);
            md[k] = m;
            if (m > bd) { bd = m; bi = gi0 + (k << 8); }  // strict >: first index wins
        }
        unsigned long long db  = (unsigned long long)__double_as_longlong(bd); // bd>=0
        unsigned long long key = 0x8000000000000000ull
                               | (db & 0xFFFFFFFFFFFF0000ull)
                               | (unsigned long long)((~bi) & 0xFFFF);
#pragma unroll
        for (int off = 32; off > 0; off >>= 1) {
            unsigned long long o = __shfl_xor(key, off, 64);
            if (o > key) key = o;
        }
        if ((t & 63) == 0) wbest[t >> 6] = key;
        __syncthreads();                                   // bar1
        if (t == 0) {
            unsigned long long k0 = wbest[0];
            if (wbest[1] > k0) k0 = wbest[1];
            if (wbest[2] > k0) k0 = wbest[2];
            if (wbest[3] > k0) k0 = wbest[3];
            __hip_atomic_store(slot_it + wg, k0, __ATOMIC_RELAXED, __HIP_MEMORY_SCOPE_AGENT);
        }
        if (t < 16) {
            unsigned long long v;
            v = __hip_atomic_load(slot_it + t, __ATOMIC_RELAXED, __HIP_MEMORY_SCOPE_AGENT);
            while (v == 0) {
                __builtin_amdgcn_s_sleep(1);
                v = __hip_atomic_load(slot_it + t, __ATOMIC_RELAXED, __HIP_MEMORY_SCOPE_AGENT);
            }
            skey[t] = v;
        }
        __syncthreads();                                   // bar2
        unsigned long long bk = skey[0];
#pragma unroll
        for (int j = 1; j < 16; ++j) if (skey[j] > bk) bk = skey[j];
        int sel = (int)((~bk) & 0xFFFFull);
        cx = (double)P[3*sel+0]; cy = (double)P[3*sel+1]; cz = (double)P[3*sel+2];
        if (wg == 0 && t == 0) {
            float* c = centers + b*(NP*3) + (it+1)*3;
            c[0] = P[3*sel+0]; c[1] = P[3*sel+1]; c[2] = P[3*sel+2];
        }
        slot_it += 16;
        // no trailing barrier: next round's bar1 orders skey/wbest reuse
    }
}

// ---------------------------------------------------------------------------
// KNN pass: 2048 WGs x 256 thr. blockIdx: b=&15 (XCD-local batch), w=(>>4)&15
// (center group of 4), s=>>8 (slice of 8192 pts). Hot loops process 4 points
// per thread per iteration via 3 independent float4 loads (48B/lane) -> 4x
// memory-latency amortization (R6's scalar 12B/pt loop was latency-bound at
// VALUBusy 43%). Pass 1: f32 per-thread top-2 -> WG pool (512/center) ->
// theta = pool 32nd + 4e-3 (pool values are real distances of distinct
// points -> >=32 below theta; margin >> f32 err ~1e-5). Pass 2: f32 rescan,
// record indices only. Phase 3: wave g computes exact f64 keys for <=CAP
// candidates (3/lane), extracts top-32 sorted -> gkeys[c][s][32].
// ---------------------------------------------------------------------------
__global__ __launch_bounds__(256, 4)
void knn_pass(const float* __restrict__ pts,
              const float* __restrict__ centers,
              unsigned long long* __restrict__ gkeys)   // [1024][8][32]
{
    const int t    = threadIdx.x;
    const int lane = t & 63;
    const int wid  = t >> 6;             // 0..3
    const int b    = blockIdx.x & 15;
    const int w    = (blockIdx.x >> 4) & 15;
    const int s    = blockIdx.x >> 8;    // 0..7
    const float* __restrict__ P = pts + (size_t)b * NPTS * 3;
    const int sbase = s * SLICE_PTS;
    const float4* __restrict__ P4 = (const float4*)(P + 3 * sbase);

    float cxf[4], cyf[4], czf[4], c2f[4];
#pragma unroll
    for (int g = 0; g < 4; ++g) {
        int c = b * NP + w * 4 + g;
        cxf[g] = centers[3*c+0]; cyf[g] = centers[3*c+1]; czf[g] = centers[3*c+2];
        c2f[g] = cxf[g]*cxf[g] + cyf[g]*cyf[g] + czf[g]*czf[g];
    }

    __shared__ unsigned pool[4][512];
    __shared__ float    theta4[4];
    __shared__ int      cnt4[4];
    __shared__ unsigned idxbuf[4][CAP];

    // ---- pass 1: per-thread top-2 (f32), 4 pts/iter via 3 float4 loads ----
    float s0[4], s1[4];
#pragma unroll
    for (int g = 0; g < 4; ++g) { s0[g] = FLT_MAX; s1[g] = FLT_MAX; }
    for (int k = 0; k < SLICE_PTS/1024; ++k) {       // 8 iterations
        int vb = k*768 + 3*t;
        float4 A = P4[vb], B = P4[vb+1], C = P4[vb+2];
        float qx[4] = {A.x, A.w, B.z, C.y};
        float qy[4] = {A.y, B.x, B.w, C.z};
        float qz[4] = {A.z, B.y, C.x, C.w};
#pragma unroll
        for (int j = 0; j < 4; ++j) {
            float px = qx[j], py = qy[j], pz = qz[j];
            float p2 = px*px + py*py + pz*pz;
#pragma unroll
            for (int g = 0; g < 4; ++g) {
                float dt = cxf[g]*px + cyf[g]*py + czf[g]*pz;
                float d2 = (c2f[g] + p2) - 2.0f*dt;
                float mx = fmaxf(d2, s0[g]);
                s0[g] = fminf(s0[g], d2);
                s1[g] = fminf(s1[g], mx);
            }
        }
    }
#pragma unroll
    for (int g = 0; g < 4; ++g) {
        pool[g][t]       = enc32(s0[g]);
        pool[g][256 + t] = enc32(s1[g]);
    }
    if (t < 4) cnt4[t] = 0;
    __syncthreads();

    // ---- theta: wave wid finds 32nd smallest of pool[wid][0..511] ----
    {
        const int g = wid;
        unsigned e[8];
#pragma unroll
        for (int j = 0; j < 8; ++j) e[j] = pool[g][lane * 8 + j];
        unsigned ans = 0;
        for (int bit = 31; bit >= 0; --bit) {
            unsigned test = ans | ((1u << bit) - 1u);
            int cnt = 0;
#pragma unroll
            for (int j = 0; j < 8; ++j)
                cnt += (int)__popcll(__ballot(e[j] <= test));
            if (cnt < 32) ans |= (1u << bit);
        }
        if (lane == 0) theta4[g] = dec32(ans) + 4.0e-3f;
    }
    __syncthreads();
    float th[4];
#pragma unroll
    for (int g = 0; g < 4; ++g) th[g] = theta4[g];

    // ---- pass 2: f32 rescan (same unrolled loads), record indices only ----
    for (int k = 0; k < SLICE_PTS/1024; ++k) {
        int vb = k*768 + 3*t;
        float4 A = P4[vb], B = P4[vb+1], C = P4[vb+2];
        float qx[4] = {A.x, A.w, B.z, C.y};
        float qy[4] = {A.y, B.x, B.w, C.z};
        float qz[4] = {A.z, B.y, C.x, C.w};
        int ib = sbase + (k << 10) + (t << 2);
#pragma unroll
        for (int j = 0; j < 4; ++j) {
            float px = qx[j], py = qy[j], pz = qz[j];
            float p2 = px*px + py*py + pz*pz;
#pragma unroll
            for (int g = 0; g < 4; ++g) {
                float dt = cxf[g]*px + cyf[g]*py + czf[g]*pz;
                float d2 = (c2f[g] + p2) - 2.0f*dt;
                bool hit = (d2 <= th[g]);
                unsigned long long m = __ballot(hit);
                if (m) {
                    int ldr = __ffsll(m) - 1;
                    int base = 0;
                    if (lane == ldr) base = atomicAdd(&cnt4[g], (int)__popcll(m));
                    base = __shfl(base, ldr, 64);
                    if (hit) {
                        int pos = base + (int)__popcll(m & ((1ull << lane) - 1ull));
                        if (pos < CAP) idxbuf[g][pos] = (unsigned)(ib + j);
                    }
                }
            }
        }
    }
    __syncthreads();

    // ---- phase 3: wave wid -> center wid: exact f64 keys, top-32 sorted ----
    {
        const int g = wid;
        int n = cnt4[g]; if (n > CAP) n = CAP;
        double cxd, cyd, czd, c2d;
        {
#pragma clang fp contract(off)
            cxd = (double)cxf[g]; cyd = (double)cyf[g]; czd = (double)czf[g];
            c2d = (cxd*cxd + cyd*cyd) + czd*czd;
        }
        unsigned long long rg[3];
#pragma unroll
        for (int j = 0; j < 3; ++j) {
            int p_ = lane + 64*j;
            if (p_ < n) {
                unsigned i = idxbuf[g][p_];
                double d2x;
                {
#pragma clang fp contract(off)
                    double px_ = (double)P[3*i+0];
                    double py_ = (double)P[3*i+1];
                    double pz_ = (double)P[3*i+2];
                    double p2_ = (px_*px_ + py_*py_) + pz_*pz_;
                    double dt_ = (cxd*px_ + cyd*py_) + czd*pz_;
                    d2x = (c2d + p2_) - 2.0*dt_;
                }
                rg[j] = (enc64(d2x) & 0xFFFFFFFFFFFF0000ull)
                      | (unsigned long long)(i & 0xFFFF);
            } else rg[j] = SENT;
        }
        const int c = b * NP + w * 4 + g;
        unsigned long long okey = SENT;
        for (int r = 0; r < PS; ++r) {
            unsigned long long mn = rg[0]; int mp = 0;
            if (rg[1] < mn) { mn = rg[1]; mp = 1; }
            if (rg[2] < mn) { mn = rg[2]; mp = 2; }
            unsigned long long wm = mn;
#pragma unroll
            for (int off = 32; off > 0; off >>= 1) {
                unsigned long long o = __shfl_xor(wm, off, 64);
                if (o < wm) wm = o;
            }
            if (wm == mn) {               // unique owner (idx in key)
                if (mp == 0) rg[0] = SENT;
                else if (mp == 1) rg[1] = SENT;
                else rg[2] = SENT;
            }
            if (lane == r) okey = wm;
        }
        if (lane < PS)
            gkeys[((size_t)c * SLICES + s) * PS + lane] = okey;
    }
}

// ---------------------------------------------------------------------------
// Merge: 256 WGs x 256 thr; wave wid handles center b*64+grp*4+wid. Reads 8
// sorted 32-key lists (256 keys, 4/lane), 32 extraction rounds -> global
// top-32 in lax.top_k order; lanes 0..31 gather P and write patch rows.
// ---------------------------------------------------------------------------
__global__ __launch_bounds__(256, 4)
void knn_merge(const float* __restrict__ pts,
               const float* __restrict__ centers,
               const unsigned long long* __restrict__ gkeys,
               float* __restrict__ patches)
{
    const int lane = threadIdx.x & 63;
    const int wid  = threadIdx.x >> 6;
    const int b    = blockIdx.x & 15;
    const int grp  = blockIdx.x >> 4;
    const int c    = b * NP + grp * 4 + wid;
    const float* __restrict__ P = pts + (size_t)b * NPTS * 3;

    unsigned long long rg[4];
#pragma unroll
    for (int j = 0; j < 4; ++j)
        rg[j] = gkeys[(size_t)c * (SLICES*PS) + j*64 + lane];

    unsigned long long okey = SENT;
    for (int r = 0; r < PS; ++r) {
        unsigned long long mn = rg[0]; int mp = 0;
        if (rg[1] < mn) { mn = rg[1]; mp = 1; }
        if (rg[2] < mn) { mn = rg[2]; mp = 2; }
        if (rg[3] < mn) { mn = rg[3]; mp = 3; }
        unsigned long long wm = mn;
#pragma unroll
        for (int off = 32; off > 0; off >>= 1) {
            unsigned long long o = __shfl_xor(wm, off, 64);
            if (o < wm) wm = o;
        }
        if (wm == mn) {
            if (mp == 0) rg[0] = SENT;
            else if (mp == 1) rg[1] = SENT;
            else if (mp == 2) rg[2] = SENT;
            else rg[3] = SENT;
        }
        if (lane == r) okey = wm;
    }

    const float cx = centers[3*c+0], cy = centers[3*c+1], cz = centers[3*c+2];
    if (lane < PS) {
        int i = (int)(okey & 0xFFFFull);
        float* o = patches + (((size_t)c * PS) + lane) * 3;
        o[0] = P[3*i+0] - cx;
        o[1] = P[3*i+1] - cy;
        o[2] = P[3*i+2] - cz;
    }
}

extern "C" void kernel_launch(void* const* d_in, const int* in_sizes, int n_in,
                              void* d_out, int out_size, void* d_ws, size_t ws_size,
                              hipStream_t stream)
{
    const float* pts = (const float*)d_in[0];
    float* out      = (float*)d_out;
    float* patches  = out;                          // [16][64][32][3] = 98304
    float* centers  = out + (size_t)BATCH*NP*PS*3;  // [16][64][3]     = 3072

    unsigned long long* slots = (unsigned long long*)d_ws;                   // 129 KB
    unsigned long long* gkeys = (unsigned long long*)((char*)d_ws + 131072); // 2 MB

    (void)hipMemsetAsync(d_ws, 0, (size_t)BATCH * 63 * 16 * sizeof(unsigned long long), stream);
    fps_kernel<<<dim3(256), dim3(256), 0, stream>>>(pts, centers, slots);
    knn_pass<<<dim3(2048), dim3(256), 0, stream>>>(pts, centers, gkeys);
    knn_merge<<<dim3(256), dim3(256), 0, stream>>>(pts, centers, gkeys, patches);
}